// Round 23
// baseline (285.356 us; speedup 1.0000x reference)
//
#include <hip/hip_runtime.h>
#include <hip/hip_bf16.h>

#define EPSV 1e-5f

// workspace layout: [wB2][xTp][stats]
#define WB2_ELEMS (2*8*36*128*32)          // [p][nt(8)][kt(36)][nl(128)][kk(32)] bf16
#define WB2_BYTES ((size_t)WB2_ELEMS*2)    // 4,718,592
#define XTP_ELEMS (8*68*68*128)            // padded channels-last x, bf16
#define XTP_BYTES ((size_t)XTP_ELEMS*2)    // 9,469,952
#define STATS_OFF (WB2_BYTES + XTP_BYTES)  // 1024 float2 partials

// k_conv dynamic LDS: 3 A-bufs (8 KB) + 3 B-bufs (16 KB) = 73,728 B
#define CONV_LDS_BYTES (3*8192 + 3*16384)

typedef __attribute__((ext_vector_type(8))) short short8;
typedef __attribute__((ext_vector_type(4))) float f32x4;
typedef __attribute__((ext_vector_type(16))) float f32x16;

__device__ __forceinline__ void gload_lds16(const void* g, void* l) {
    __builtin_amdgcn_global_load_lds(
        (const __attribute__((address_space(1))) void*)g,
        (__attribute__((address_space(3))) void*)l, 16, 0, 0);
}

// ---------------------------------------------------------------------------
// x [8][128][64][64] f32  ->  xTp [8][68][68][128] bf16 (2-px zero halo)
__global__ __launch_bounds__(256) void k_xpad(const float* __restrict__ x,
                                              __hip_bfloat16* __restrict__ xTp) {
    int bh = blockIdx.x; int b = bh >> 6, h = bh & 63;
    __shared__ __hip_bfloat16 tile[64][130];
    int t = threadIdx.x;
#pragma unroll
    for (int i = 0; i < 32; ++i) {
        int e = (i << 8) + t; int w = e & 63; int ci = e >> 6;
        tile[w][ci] = __float2bfloat16(x[(((size_t)(b*128 + ci))*64 + h)*64 + w]);
    }
    __syncthreads();
    __hip_bfloat16* dst = xTp + ((size_t)((b*68 + h + 2)*68 + 2))*128;
#pragma unroll
    for (int i = 0; i < 32; ++i) {
        int e = (i << 8) + t; int ci = e & 127; int w = e >> 7;
        dst[w*128 + ci] = tile[w][ci];
    }
}

// ---------------------------------------------------------------------------
// w_mid [128][16][128][3][3] f32 -> wB2 [p][nt(8)][kt(36)][nl(128)][kk(32)]
__global__ void k_wrepack(const float* __restrict__ w_mid,
                          __hip_bfloat16* __restrict__ wB2) {
    int idx = blockIdx.x * 256 + threadIdx.x;
    if (idx >= WB2_ELEMS) return;
    int kk  = idx & 31;
    int nl  = (idx >> 5) & 127;
    int q   = idx >> 12;             // (p*8+nt)*36 + kt
    int kt  = q % 36;
    int pnt = q / 36;
    int nt  = pnt & 7, p = pnt >> 3;
    int c = ((nt*8 + (nl >> 4)) << 1) + p;
    int m = nl & 15;
    int k = kt*32 + kk;
    int tap = k >> 7, ci = k & 127;
    wB2[idx] = __float2bfloat16(w_mid[((size_t)((c*16 + m)*128 + ci))*9 + tap]);
}

// ---------------------------------------------------------------------------
// Implicit-GEMM conv: R14 skeleton (BM=128, BN=256, BK=32, 4 waves 2Mx2N,
// 3 rotating buffer sets, counted vmcnt(6) distance-2, one barrier/ktile,
// 2 blocks/CU) with the compute core on v_mfma_f32_32x32x16_bf16:
// wave tile = 2 row-tiles x 4 col-tiles of 32, acc[2][4] f32x16 (128 AGPR),
// 16 MFMA/ktile (half the instructions, 2382-TF-ceiling shape).
// Operand layout (K-doubling symmetry w/ verified 16x16x32):
//   A: row = lane&31, k = (lane>>5)*8 + j ; B symmetric;
//   C/D: col = lane&31, row = (r&3) + 8*(r>>2) + 4*(lane>>5)  [m74/m101].
__global__ __launch_bounds__(256, 2) void k_conv(
    const __hip_bfloat16* __restrict__ xTp,
    const __hip_bfloat16* __restrict__ wB2,
    const float* __restrict__ w_pt,
    const float* __restrict__ b_pt,
    float* __restrict__ y) {
    extern __shared__ char smem[];
    __hip_bfloat16* Alds = (__hip_bfloat16*)smem;              // 3 x 8 KB
    __hip_bfloat16* Blds = (__hip_bfloat16*)(smem + 3*8192);   // 3 x 16 KB

    // XCD combo = (p, nt-pair): per-XCD B slice = 576 KB (R12/R14-proven)
    const int combo = blockIdx.x & 7;
    const int p   = combo & 1;
    const int ntp = combo >> 1;          // nt-pair 0..3 (cols ntp*256..+255)
    const int mt  = blockIdx.x >> 3;     // spatial tile 0..255
    const int dil = 1 + p;

    const int t = threadIdx.x;
    const int lane = t & 63;
    const int wave = t >> 6;
    const int wm = wave >> 1, wn = wave & 1;

    const int rsub = t >> 2;                              // staging row (0..63)
    const int ksub = (((t & 3) ^ ((t >> 3) & 3)) << 3);   // src-side swizzled slot

    // A source base pointers (tap center, k-chunk 0) per 64-row pass (R10/R14)
    const __hip_bfloat16* abase0;
    const __hip_bfloat16* abase1;
    {
        int s0 = mt*128 + rsub;
        int s1 = s0 + 64;
        abase0 = xTp + ((size_t)(((s0>>12)*68 + ((s0>>6)&63) + 2)*68 + (s0&63) + 2))*128 + ksub;
        abase1 = xTp + ((size_t)(((s1>>12)*68 + ((s1>>6)&63) + 2)*68 + (s1&63) + 2))*128 + ksub;
    }
    // B source: nt0 = ntp*2 slab; nt1 = +36*4096 elems (R14-proven)
    const __hip_bfloat16* bbase = wB2 + (size_t)p*(8*36*4096)
                                + (size_t)(ntp*2)*(36*4096) + rsub*32 + ksub;

    // staging: 6 x gload_lds per thread per ktile (A 8 KB + B 16 KB) — R14
#define ISSUE(u, bufi) do {                                                   \
    const int tap_ = (u) >> 2, kc_ = (u) & 3;                                 \
    const int kh_ = tap_/3 - 1, kw_ = tap_%3 - 1;                             \
    const int toff_ = dil*(128*(kh_*68 + kw_)) + kc_*32;                      \
    gload_lds16(abase0 + toff_, (char*)Alds + (bufi)*8192 + t*16);            \
    gload_lds16(abase1 + toff_, (char*)Alds + (bufi)*8192 + 4096 + t*16);     \
    gload_lds16(bbase + (size_t)(u)*4096,                 (char*)Blds + (bufi)*16384 + t*16);         \
    gload_lds16(bbase + (size_t)(u)*4096 + 2048,          (char*)Blds + (bufi)*16384 + 4096 + t*16);  \
    gload_lds16(bbase + (size_t)(u)*4096 + 147456,        (char*)Blds + (bufi)*16384 + 8192 + t*16);  \
    gload_lds16(bbase + (size_t)(u)*4096 + 147456 + 2048, (char*)Blds + (bufi)*16384 + 12288 + t*16); \
  } while (0)

    f32x16 acc[2][4];
#pragma unroll
    for (int i = 0; i < 2; ++i)
#pragma unroll
        for (int j = 0; j < 4; ++j)
#pragma unroll
            for (int r = 0; r < 16; ++r) acc[i][j][r] = 0.f;

    // 32-wide lane decode
    const int l31 = lane & 31;
    const int lh  = lane >> 5;                 // k-half selector within frag
    const int skey = (l31 >> 1) & 3;           // read-side swizzle key (base%32==0)

    // fragment element offsets (elems): A row = wm*64 + at*32 + l31;
    // slot logical = kh*2 + lh, phys = logical ^ skey
    int aoff[2][2], boff[4][2];
#pragma unroll
    for (int at = 0; at < 2; ++at)
#pragma unroll
        for (int kh = 0; kh < 2; ++kh)
            aoff[at][kh] = (wm*64 + at*32 + l31)*32 + (((kh*2 + lh) ^ skey) << 3);
#pragma unroll
    for (int bt = 0; bt < 4; ++bt)
#pragma unroll
        for (int kh = 0; kh < 2; ++kh)
            boff[bt][kh] = (wn*128 + bt*32 + l31)*32 + (((kh*2 + lh) ^ skey) << 3);

    // prologue: issue ktiles 0 and 1
    ISSUE(0, 0);
    ISSUE(1, 1);

#pragma unroll
    for (int u = 0; u < 36; ++u) {
        const int bi  = u % 3;
        const int bi2 = (u + 2) % 3;
        if (u < 35) asm volatile("s_waitcnt vmcnt(6)" ::: "memory");
        else        asm volatile("s_waitcnt vmcnt(0)" ::: "memory");
        __builtin_amdgcn_s_barrier();
        __builtin_amdgcn_sched_barrier(0);
        if (u + 2 < 36) ISSUE(u + 2, bi2);
        short8 af[2][2], bf[4][2];
#pragma unroll
        for (int at = 0; at < 2; ++at)
#pragma unroll
            for (int kh = 0; kh < 2; ++kh)
                af[at][kh] = *(const short8*)(Alds + bi*4096 + aoff[at][kh]);
#pragma unroll
        for (int bt = 0; bt < 4; ++bt)
#pragma unroll
            for (int kh = 0; kh < 2; ++kh)
                bf[bt][kh] = *(const short8*)(Blds + bi*8192 + boff[bt][kh]);
        __builtin_amdgcn_s_setprio(1);
#pragma unroll
        for (int kh = 0; kh < 2; ++kh)
#pragma unroll
            for (int at = 0; at < 2; ++at)
#pragma unroll
                for (int bt = 0; bt < 4; ++bt)
                    acc[at][bt] = __builtin_amdgcn_mfma_f32_32x32x16_bf16(
                        af[at][kh], bf[bt][kh], acc[at][bt], 0, 0, 0);
        __builtin_amdgcn_s_setprio(0);
    }
#undef ISSUE

    // epilogue: leaky -> *w_pt -> reduce over m (16 lanes) -> +b_pt -> y
    // C/D: col = l31 (B col), row = (r&3) + 8*(r>>2) + 4*lh (A row within 32)
#pragma unroll
    for (int bt = 0; bt < 4; ++bt) {
        int colbase = wn*128 + bt*32;              // multiple of 32
        int n_g = (ntp*2 + ((colbase + l31) >> 7))*128 + ((colbase + l31) & 127);
        int c = ((n_g >> 4) << 1) + p;             // uniform per 16-lane group
        int m = l31 & 15;
        float wp = w_pt[c*16 + m];
        float bp = b_pt[c];
#pragma unroll
        for (int at = 0; at < 2; ++at) {
#pragma unroll
            for (int r = 0; r < 16; ++r) {
                float v = acc[at][bt][r];
                v = v >= 0.f ? v : 0.1f*v;
                v *= wp;
                v += __shfl_xor(v, 1);
                v += __shfl_xor(v, 2);
                v += __shfl_xor(v, 4);
                v += __shfl_xor(v, 8);
                if (m == 0) {
                    int row = (r & 3) + 8*(r >> 2) + 4*lh;
                    int s = mt*128 + wm*64 + at*32 + row;
                    int b = s >> 12, hw = s & 4095;
                    y[(size_t)(b*128 + c)*4096 + hw] = v + bp;
                }
            }
        }
    }
}

// ---------------------------------------------------------------------------
// per-(b,c)-plane partial sums (float4 loads, no atomics, deterministic)
__global__ __launch_bounds__(256) void k_ystat(const float* __restrict__ y,
                                               float2* __restrict__ partials) {
    int P = blockIdx.x;                 // plane = b*128 + c
    const float4* base = (const float4*)(y + (size_t)P*4096);
    int t = threadIdx.x;
    float s = 0.f, s2 = 0.f;
#pragma unroll
    for (int i = 0; i < 4; ++i) {
        float4 v = base[t + i*256];
        s  += v.x + v.y + v.z + v.w;
        s2 += v.x*v.x + v.y*v.y + v.z*v.z + v.w*v.w;
    }
#pragma unroll
    for (int o = 32; o; o >>= 1) { s += __shfl_down(s, o); s2 += __shfl_down(s2, o); }
    __shared__ float ss[4], ss2[4];
    if ((t & 63) == 0) { ss[t >> 6] = s; ss2[t >> 6] = s2; }
    __syncthreads();
    if (t == 0)
        partials[P] = make_float2(ss[0]+ss[1]+ss[2]+ss[3], ss2[0]+ss2[1]+ss2[2]+ss2[3]);
}

// BN finalize + apply + ReLU. Block covers 256 float4 = quarter of one plane.
__global__ __launch_bounds__(256) void k_bn_apply(float* __restrict__ y,
                                                  const float2* __restrict__ partials,
                                                  const float* __restrict__ gamma,
                                                  const float* __restrict__ beta) {
    int bid = blockIdx.x;
    int c = (bid >> 2) & 127;
    float s = 0.f, s2 = 0.f;
#pragma unroll
    for (int b = 0; b < 8; ++b) {
        float2 pr = partials[b*128 + c];
        s += pr.x; s2 += pr.y;
    }
    float mean = s * (1.f/32768.f);
    float var  = s2 * (1.f/32768.f) - mean*mean;
    float scale = gamma[c] * rsqrtf(var + EPSV);
    float shift = beta[c] - mean*scale;
    float4* y4 = (float4*)y;
    int idx = bid*256 + threadIdx.x;
    float4 v = y4[idx];
    v.x = fmaxf(v.x*scale + shift, 0.f);
    v.y = fmaxf(v.y*scale + shift, 0.f);
    v.z = fmaxf(v.z*scale + shift, 0.f);
    v.w = fmaxf(v.w*scale + shift, 0.f);
    y4[idx] = v;
}

// ---------------------------------------------------------------------------
extern "C" void kernel_launch(void* const* d_in, const int* in_sizes, int n_in,
                              void* d_out, int out_size, void* d_ws, size_t ws_size,
                              hipStream_t stream) {
    const float* x     = (const float*)d_in[0];
    const float* w_mid = (const float*)d_in[1];
    const float* w_pt  = (const float*)d_in[2];
    const float* b_pt  = (const float*)d_in[3];
    const float* gamma = (const float*)d_in[4];
    const float* beta  = (const float*)d_in[5];
    float* y = (float*)d_out;

    __hip_bfloat16* wB2 = (__hip_bfloat16*)d_ws;
    __hip_bfloat16* xTp = (__hip_bfloat16*)((char*)d_ws + WB2_BYTES);
    float2* partials    = (float2*)((char*)d_ws + STATS_OFF);

    // opt in to >64 KB dynamic LDS for k_conv (host-side, graph-capture-safe)
    (void)hipFuncSetAttribute((const void*)k_conv,
                              hipFuncAttributeMaxDynamicSharedMemorySize,
                              CONV_LDS_BYTES);

    hipMemsetAsync(xTp, 0, XTP_BYTES, stream);                  // zero halo
    k_xpad<<<512, 256, 0, stream>>>(x, xTp);
    k_wrepack<<<(WB2_ELEMS + 255) / 256, 256, 0, stream>>>(w_mid, wB2);
    k_conv<<<2048, 256, CONV_LDS_BYTES, stream>>>(xTp, wB2, w_pt, b_pt, y);
    k_ystat<<<1024, 256, 0, stream>>>(y, partials);
    k_bn_apply<<<4096, 256, 0, stream>>>(y, partials, gamma, beta);
}

// Round 24
// 190.139 us; speedup vs baseline: 1.5008x; 1.5008x over previous
//
#include <hip/hip_runtime.h>
#include <hip/hip_bf16.h>

#define EPSV 1e-5f

// workspace layout: [wB2][xTp][stats]
#define WB2_ELEMS (2*4*36*256*32)          // [p][nt(4)][kt(36)][nl(256)][kk(32)] bf16
#define WB2_BYTES ((size_t)WB2_ELEMS*2)    // 4,718,592
#define XTP_ELEMS (8*68*68*128)            // padded channels-last x, bf16
#define XTP_BYTES ((size_t)XTP_ELEMS*2)    // 9,469,952
#define STATS_OFF (WB2_BYTES + XTP_BYTES)  // 1024 float2 partials

// k_conv dynamic LDS: 4 dbuf x (A 16 KB + B 16 KB) = 128 KB
#define CONV_LDS_BYTES (131072)

typedef __attribute__((ext_vector_type(8))) short short8;
typedef __attribute__((ext_vector_type(4))) float f32x4;

__device__ __forceinline__ void gload_lds16(const void* g, void* l) {
    __builtin_amdgcn_global_load_lds(
        (const __attribute__((address_space(1))) void*)g,
        (__attribute__((address_space(3))) void*)l, 16, 0, 0);
}

// ---------------------------------------------------------------------------
// x [8][128][64][64] f32  ->  xTp [8][68][68][128] bf16 (2-px zero halo)
__global__ __launch_bounds__(256) void k_xpad(const float* __restrict__ x,
                                              __hip_bfloat16* __restrict__ xTp) {
    int bh = blockIdx.x; int b = bh >> 6, h = bh & 63;
    __shared__ __hip_bfloat16 tile[64][130];
    int t = threadIdx.x;
#pragma unroll
    for (int i = 0; i < 32; ++i) {
        int e = (i << 8) + t; int w = e & 63; int ci = e >> 6;
        tile[w][ci] = __float2bfloat16(x[(((size_t)(b*128 + ci))*64 + h)*64 + w]);
    }
    __syncthreads();
    __hip_bfloat16* dst = xTp + ((size_t)((b*68 + h + 2)*68 + 2))*128;
#pragma unroll
    for (int i = 0; i < 32; ++i) {
        int e = (i << 8) + t; int ci = e & 127; int w = e >> 7;
        dst[w*128 + ci] = tile[w][ci];
    }
}

// ---------------------------------------------------------------------------
// w_mid [128][16][128][3][3] f32 -> wB2 [p][nt(4)][kt(36)][nl(256)][kk(32)]
// NEW column meaning: n = c_outer*64 + m*4 + c_inner, so the m-reduction in
// the epilogue is over j-tiles (in-register) + 2 shuffles, not 4 shuffles.
__global__ void k_wrepack(const float* __restrict__ w_mid,
                          __hip_bfloat16* __restrict__ wB2) {
    int idx = blockIdx.x * 256 + threadIdx.x;
    if (idx >= WB2_ELEMS) return;
    int kk  = idx & 31;
    int nl  = (idx >> 5) & 255;
    int q   = idx >> 13;             // (p*4+nt)*36 + kt
    int kt  = q % 36;
    int pnt = q / 36;                // 0..7
    int nt  = pnt & 3, p = pnt >> 2;
    int c_local = (nt*4 + (nl >> 6))*4 + (nl & 3);   // c_outer*4 + c_inner
    int m = (nl >> 2) & 15;
    int c = 2*c_local + p;
    int k = kt*32 + kk;
    int tap = k >> 7, ci = k & 127;
    wB2[idx] = __float2bfloat16(w_mid[((size_t)((c*16 + m)*128 + ci))*9 + tap]);
}

// ---------------------------------------------------------------------------
// Implicit-GEMM conv — R21 8-phase skeleton VERBATIM (best: 218 us); only the
// epilogue changed: column remap makes the m-reduce = sum over j (registers)
// + 2 shuffles, cutting epilogue DS traffic 8x (4096 -> 512 wave-instr/block).
__global__ __launch_bounds__(512, 2) void k_conv(
    const __hip_bfloat16* __restrict__ xTp,
    const __hip_bfloat16* __restrict__ wB2,
    const float* __restrict__ w_pt,
    const float* __restrict__ b_pt,
    float* __restrict__ y) {
    extern __shared__ char smem[];
    __hip_bfloat16* Ae = (__hip_bfloat16*)smem;              // 4 x 8192 elems
    __hip_bfloat16* Be = (__hip_bfloat16*)(smem + 65536);    // 4 x 8192 elems

    const int combo = blockIdx.x & 7;      // XCD: one (p, nt) each
    const int p  = combo & 1;
    const int nt = combo >> 1;             // 0..3
    const int mt = blockIdx.x >> 3;        // 0..127 (256 spatial rows each)
    const int dil = 1 + p;

    const int t = threadIdx.x;             // 0..511
    const int lane = t & 63;
    const int wave = t >> 6;               // 0..7
    const int wm = wave >> 2;              // 0..1
    const int wn = wave & 3;               // 0..3
    const int lm = lane & 15, lg = lane >> 4;

    // ---- staging addressing (R21-verbatim) ----
    const int rsub = t >> 2;                              // row 0..127
    const int ksub = (((t & 3) ^ ((t >> 3) & 3)) << 3);   // src-side swizzled slot
    const __hip_bfloat16* abase0;
    const __hip_bfloat16* abase1;
    {
        int s0 = mt*256 + rsub;
        int s1 = s0 + 128;
        abase0 = xTp + ((size_t)(((s0>>12)*68 + ((s0>>6)&63) + 2)*68 + (s0&63) + 2))*128 + ksub;
        abase1 = xTp + ((size_t)(((s1>>12)*68 + ((s1>>6)&63) + 2)*68 + (s1&63) + 2))*128 + ksub;
    }
    const __hip_bfloat16* bbase = wB2 + (size_t)(p*4 + nt)*(36*8192)
                                + rsub*32 + ksub;

    // ---- ds-read offsets (R21-verbatim swizzle) ----
    const int sslot = (lg ^ ((lm >> 1) & 3)) << 3;
    const int aoffb = (wm*128 + lm)*32 + sslot;     // + i*512 + dbuf*8192
    const int boffb = (wn*64 + lm)*32 + sslot;      // + j*512 + dbuf*8192

    f32x4 acc[8][4];
#pragma unroll
    for (int i = 0; i < 8; ++i)
#pragma unroll
        for (int j = 0; j < 4; ++j) acc[i][j] = (f32x4){0.f, 0.f, 0.f, 0.f};

    // ---- prologue: stage kt0 -> dbuf0, kt1 -> dbuf1 (8 loads), vmcnt(4) ----
    {
        const int t0 = -dil*8832;    // tap 0: kh=-1, kw=-1; ci0 = 0
        gload_lds16(abase0 + t0,      smem           + (0*512 + t)*16);
        gload_lds16(abase1 + t0,      smem           + (1*512 + t)*16);
        gload_lds16(bbase,            smem + 65536   + (0*512 + t)*16);
        gload_lds16(bbase + 4096,     smem + 65536   + (1*512 + t)*16);
        gload_lds16(abase0 + t0 + 32, smem + 16384   + (0*512 + t)*16);
        gload_lds16(abase1 + t0 + 32, smem + 16384   + (1*512 + t)*16);
        gload_lds16(bbase + 8192,     smem + 81920   + (0*512 + t)*16);
        gload_lds16(bbase + 12288,    smem + 81920   + (1*512 + t)*16);
    }
    asm volatile("s_waitcnt vmcnt(4)" ::: "memory");   // kt0 resident, kt1 in flight
    __builtin_amdgcn_s_barrier();
    __builtin_amdgcn_sched_barrier(0);

    // ---- K-loop: kt = 4*vv + ss, 2 phases (q) per ktile (R21-verbatim) ----
#pragma unroll 1
    for (int vv = 0; vv < 9; ++vv) {
        const int q3c = (vv*11) >> 5;
        const int toff_c = dil*128*((q3c - 1)*68 + (vv - 3*q3c - 1));
        const int vn = vv + 1;
        const int q3n = (vn*11) >> 5;
        const int toff_n = dil*128*((q3n - 1)*68 + (vn - 3*q3n - 1));
#pragma unroll
        for (int ss = 0; ss < 4; ++ss) {
            const int d  = ss;                 // dbuf of ktile kt (static)
            const int d2 = (ss + 2) & 3;       // dbuf staged (static)
            const bool do_stage = (vv < 8) || (ss < 2);   // kt+2 < 36
            short8 bf[4];
            short8 af[4];
#pragma unroll
            for (int q = 0; q < 2; ++q) {
                if (q == 0) {
#pragma unroll
                    for (int j = 0; j < 4; ++j)
                        bf[j] = *(const short8*)(Be + d*8192 + boffb + j*512);
                }
#pragma unroll
                for (int ii = 0; ii < 4; ++ii)
                    af[ii] = *(const short8*)(Ae + d*8192 + aoffb + (q*4 + ii)*512);
                if (do_stage) {
                    if (q == 0) {
                        const int aoff = (ss < 2) ? (toff_c + (ss + 2)*32)
                                                  : (toff_n + (ss - 2)*32);
                        gload_lds16(abase0 + aoff, smem + d2*16384 + (0*512 + t)*16);
                        gload_lds16(abase1 + aoff, smem + d2*16384 + (1*512 + t)*16);
                    } else {
                        const size_t bo = (size_t)(4*vv + ss + 2)*8192;
                        gload_lds16(bbase + bo,        smem + 65536 + d2*16384 + (0*512 + t)*16);
                        gload_lds16(bbase + bo + 4096, smem + 65536 + d2*16384 + (1*512 + t)*16);
                    }
                }
                if (q == 1) {
                    if (ss == 2) {
                        if (vv == 8) asm volatile("s_waitcnt vmcnt(0)" ::: "memory");
                        else         asm volatile("s_waitcnt vmcnt(4)" ::: "memory");
                    } else {
                        asm volatile("s_waitcnt vmcnt(4)" ::: "memory");
                    }
                }
                __builtin_amdgcn_s_barrier();
                asm volatile("s_waitcnt lgkmcnt(0)" ::: "memory");
                __builtin_amdgcn_sched_barrier(0);
                __builtin_amdgcn_s_setprio(1);
#pragma unroll
                for (int ii = 0; ii < 4; ++ii)
#pragma unroll
                    for (int j = 0; j < 4; ++j)
                        acc[q*4 + ii][j] = __builtin_amdgcn_mfma_f32_16x16x32_bf16(
                            af[ii], bf[j], acc[q*4 + ii][j], 0, 0, 0);
                __builtin_amdgcn_s_setprio(0);
            }
        }
    }

    // ---- NEW epilogue: leaky -> *w_pt -> sum over j (regs) -> 2 shuffles ----
    // wave's 64 cols = c_outer (uniform) x {m = j*4 + (lm>>2)} x {ci = lm&3}
    {
        const int ci_ = lm & 3;
        const int mg  = lm >> 2;                       // m sub-index in lanes
        const int c   = (((nt*4 + wn)*4 + ci_) << 1) + p;
        const float bp = b_pt[c];
        float wpj[4];
#pragma unroll
        for (int j = 0; j < 4; ++j)
            wpj[j] = w_pt[c*16 + j*4 + mg];
#pragma unroll
        for (int i = 0; i < 8; ++i) {
#pragma unroll
            for (int r = 0; r < 4; ++r) {
                float s = 0.f;
#pragma unroll
                for (int j = 0; j < 4; ++j) {
                    float v = acc[i][j][r];
                    v = v >= 0.f ? v : 0.1f*v;
                    s += v * wpj[j];
                }
                s += __shfl_xor(s, 4);
                s += __shfl_xor(s, 8);
                if (mg == 0) {
                    int srow = mt*256 + wm*128 + i*16 + lg*4 + r;
                    int b = srow >> 12, hw = srow & 4095;
                    y[(size_t)(b*128 + c)*4096 + hw] = s + bp;
                }
            }
        }
    }
}

// ---------------------------------------------------------------------------
// per-(b,c)-plane partial sums (float4 loads, no atomics, deterministic)
__global__ __launch_bounds__(256) void k_ystat(const float* __restrict__ y,
                                               float2* __restrict__ partials) {
    int P = blockIdx.x;                 // plane = b*128 + c
    const float4* base = (const float4*)(y + (size_t)P*4096);
    int t = threadIdx.x;
    float s = 0.f, s2 = 0.f;
#pragma unroll
    for (int i = 0; i < 4; ++i) {
        float4 v = base[t + i*256];
        s  += v.x + v.y + v.z + v.w;
        s2 += v.x*v.x + v.y*v.y + v.z*v.z + v.w*v.w;
    }
#pragma unroll
    for (int o = 32; o; o >>= 1) { s += __shfl_down(s, o); s2 += __shfl_down(s2, o); }
    __shared__ float ss[4], ss2[4];
    if ((t & 63) == 0) { ss[t >> 6] = s; ss2[t >> 6] = s2; }
    __syncthreads();
    if (t == 0)
        partials[P] = make_float2(ss[0]+ss[1]+ss[2]+ss[3], ss2[0]+ss2[1]+ss2[2]+ss2[3]);
}

// BN finalize + apply + ReLU. Block covers 256 float4 = quarter of one plane.
__global__ __launch_bounds__(256) void k_bn_apply(float* __restrict__ y,
                                                  const float2* __restrict__ partials,
                                                  const float* __restrict__ gamma,
                                                  const float* __restrict__ beta) {
    int bid = blockIdx.x;
    int c = (bid >> 2) & 127;
    float s = 0.f, s2 = 0.f;
#pragma unroll
    for (int b = 0; b < 8; ++b) {
        float2 pr = partials[b*128 + c];
        s += pr.x; s2 += pr.y;
    }
    float mean = s * (1.f/32768.f);
    float var  = s2 * (1.f/32768.f) - mean*mean;
    float scale = gamma[c] * rsqrtf(var + EPSV);
    float shift = beta[c] - mean*scale;
    float4* y4 = (float4*)y;
    int idx = bid*256 + threadIdx.x;
    float4 v = y4[idx];
    v.x = fmaxf(v.x*scale + shift, 0.f);
    v.y = fmaxf(v.y*scale + shift, 0.f);
    v.z = fmaxf(v.z*scale + shift, 0.f);
    v.w = fmaxf(v.w*scale + shift, 0.f);
    y4[idx] = v;
}

// ---------------------------------------------------------------------------
extern "C" void kernel_launch(void* const* d_in, const int* in_sizes, int n_in,
                              void* d_out, int out_size, void* d_ws, size_t ws_size,
                              hipStream_t stream) {
    const float* x     = (const float*)d_in[0];
    const float* w_mid = (const float*)d_in[1];
    const float* w_pt  = (const float*)d_in[2];
    const float* b_pt  = (const float*)d_in[3];
    const float* gamma = (const float*)d_in[4];
    const float* beta  = (const float*)d_in[5];
    float* y = (float*)d_out;

    __hip_bfloat16* wB2 = (__hip_bfloat16*)d_ws;
    __hip_bfloat16* xTp = (__hip_bfloat16*)((char*)d_ws + WB2_BYTES);
    float2* partials    = (float2*)((char*)d_ws + STATS_OFF);

    // opt in to >64 KB dynamic LDS for k_conv (host-side, graph-capture-safe)
    (void)hipFuncSetAttribute((const void*)k_conv,
                              hipFuncAttributeMaxDynamicSharedMemorySize,
                              CONV_LDS_BYTES);

    hipMemsetAsync(xTp, 0, XTP_BYTES, stream);                  // zero halo
    k_xpad<<<512, 256, 0, stream>>>(x, xTp);
    k_wrepack<<<(WB2_ELEMS + 255) / 256, 256, 0, stream>>>(w_mid, wB2);
    k_conv<<<1024, 512, CONV_LDS_BYTES, stream>>>(xTp, wB2, w_pt, b_pt, y);
    k_ystat<<<1024, 256, 0, stream>>>(y, partials);
    k_bn_apply<<<4096, 256, 0, stream>>>(y, partials, gamma, beta);
}